// Round 12
// baseline (277.346 us; speedup 1.0000x reference)
//
#include <hip/hip_runtime.h>
#include <cstddef>
#include <cmath>

#define NB  4096
#define TT  200
#define DD  64
#define NH1 80
#define NH2 40

typedef _Float16 half8 __attribute__((ext_vector_type(8)));
typedef float    f32x4 __attribute__((ext_vector_type(4)));

// ---- workspace layout (bytes) ----
// wQh [4096][80] f32 : q@(W1a+W1c) + b1
// wF1 : layer-1 B fragments, lane-major: [(n*4+s)*64 + lane] -> half8  (20480 B)
// wF2 : layer-2 B fragments, lane-major: [(n*3+s)*64 + lane] -> half8  (9216 B)
static const size_t OFF_QH = 0;
static const size_t OFF_F1 = (size_t)NB * NH1 * 4;
static const size_t OFF_F2 = OFF_F1 + (size_t)5 * 4 * 64 * 8 * 2;

__global__ void prep_weights(const float* __restrict__ W1, const float* __restrict__ W2,
                             _Float16* __restrict__ wF1, _Float16* __restrict__ wF2)
{
    const int tid = blockIdx.x * blockDim.x + threadIdx.x;
    const int stride = blockDim.x * gridDim.x;
    for (int i = tid; i < 5 * 4 * 64 * 8; i += stride) {
        const int j = i & 7, l = (i >> 3) & 63, s = (i >> 9) & 3, n = i >> 11;
        const int h  = n * 16 + (l & 15);
        const int kk = s * 32 + (l >> 4) * 8 + j;
        const float w = (kk < 64) ? (W1[(64 + kk) * NH1 + h] - W1[(128 + kk) * NH1 + h])
                                  :  W1[(128 + kk) * NH1 + h];
        wF1[i] = (_Float16)w;
    }
    for (int i = tid; i < 3 * 3 * 64 * 8; i += stride) {
        const int j = i & 7, l = (i >> 3) & 63;
        const int s = (i >> 9) % 3, n = i / 1536;
        const int kk = s * 32 + (l >> 4) * 8 + j;
        const int n2 = n * 16 + (l & 15);
        const float w = (kk < NH1 && n2 < NH2) ? W2[kk * NH2 + n2] : 0.f;
        wF2[i] = (_Float16)w;
    }
}

__global__ void prep_qh(const float* __restrict__ q, const float* __restrict__ W1,
                        const float* __restrict__ b1, float* __restrict__ wQh)
{
    const int idx = blockIdx.x * blockDim.x + threadIdx.x;
    if (idx >= NB * NH1) return;
    const int b = idx / NH1;
    const int h = idx - b * NH1;
    const float* qb = q + (size_t)b * DD;
    float acc = b1[h];
#pragma unroll 8
    for (int d = 0; d < DD; ++d)
        acc += qb[d] * (W1[d * NH1 + h] + W1[(128 + d) * NH1 + h]);
    wQh[idx] = acc;
}

// one wave per b; group-split online softmax; weights + q(fp16) in LDS;
// no k prefetch -> minimal arch-VGPR live set, targets the (256,3) cap
__global__ __launch_bounds__(256, 3)
void attn_main(const float* __restrict__ q, const float* __restrict__ k,
               const float* __restrict__ v, const int* __restrict__ mask,
               const float* __restrict__ Wf, const float* __restrict__ b2g,
               const float* __restrict__ bf,
               const float* __restrict__ wQh, const _Float16* __restrict__ wF1,
               const _Float16* __restrict__ wF2, float* __restrict__ out)
{
    __shared__ __align__(16) _Float16 sWF1[5 * 4 * 64 * 8];   // 20480 B
    __shared__ __align__(16) _Float16 sWF2[3 * 3 * 64 * 8];   //  9216 B
    __shared__ __align__(16) char sH1[4 * 3072];              // per-wave h1 (12288 B)
    __shared__ __align__(16) float sBias[4][208];             //  3328 B
    __shared__ __align__(16) _Float16 sQ16[4 * 64];           //   512 B (per-wave q, fp16)

    const int tid  = threadIdx.x;
    const int wid  = tid >> 6;
    const int lane = tid & 63;
    const int lr   = lane & 15;
    const int lg   = lane >> 4;
    const int b    = blockIdx.x * 4 + wid;      // each wave owns one batch row
    const int d0   = lr * 4;                    // this lane's v/out column slice
    const float bfv = bf[0];

    // stage weight fragments into LDS (block-shared)
    {
        f32x4* dst1 = (f32x4*)sWF1;
        const f32x4* src1 = (const f32x4*)wF1;
        for (int i = tid; i < 1280; i += 256) dst1[i] = src1[i];
        f32x4* dst2 = (f32x4*)sWF2;
        const f32x4* src2 = (const f32x4*)wF2;
        for (int i = tid; i < 576; i += 256) dst2[i] = src2[i];
    }

    // per-wave q in fp16 LDS (one element per lane)
    sQ16[wid * 64 + lane] = (_Float16)q[(size_t)b * DD + lane];

    // per-wave mask bias: +big = keep, CONST_MIN = masked, -inf = pad rows (t>=200)
    for (int i = lane; i < 208; i += 64) {
        float bv;
        if (i < TT) bv = mask[(size_t)b * TT + i] ? 3.0e38f : -4294967295.0f;
        else        bv = -INFINITY;
        sBias[wid][i] = bv;
    }

    // per-lane slices of qh / Wf / b2
    float qhr[5];
#pragma unroll
    for (int n = 0; n < 5; ++n) qhr[n] = wQh[(size_t)b * NH1 + n * 16 + lr];
    float wfr[3], bbr[3];
#pragma unroll
    for (int n = 0; n < 3; ++n) {
        const int hc = n * 16 + lr;
        wfr[n] = (hc < NH2) ? Wf[hc]  : 0.f;
        bbr[n] = (hc < NH2) ? b2g[hc] : 0.f;
    }

    // zero-pad my wave's h1 cols 80..95 (slots 10,11), swizzled
    char* myH1 = sH1 + wid * 3072;
    if (lane < 32) {
        const int row = lane >> 1;
        const int slotL = 10 + (lane & 1);
        const f32x4 z4 = {};
        *(f32x4*)(myH1 + row * 192 + ((slotL ^ (row & 3)) << 4)) = z4;
    }

    __syncthreads();   // sWF1 / sWF2 / sQ16 ready

    const half8* sF1v = (const half8*)sWF1;
    const half8* sF2v = (const half8*)sWF2;
    const float* vb   = v + (size_t)b * (TT * DD);
    const float* kb   = k + (size_t)b * (TT * DD);
    const _Float16* myQ = sQ16 + wid * 64;

    // per-GROUP online softmax state (rows mt*16+lg*4+{0..3}; d-cols d0..d0+3)
    float m = -INFINITY, s = 0.f;
    f32x4 acc = {};

    for (int mt = 0; mt < 13; ++mt) {
        // ---- v loads for this tile (issued early; consumed at bottom) ----
        const int tr = mt * 16 + lg * 4;
        const f32x4 vA = *(const f32x4*)(vb + (size_t)min(tr + 0, TT - 1) * DD + d0);
        const f32x4 vB = *(const f32x4*)(vb + (size_t)min(tr + 1, TT - 1) * DD + d0);
        const f32x4 vC = *(const f32x4*)(vb + (size_t)min(tr + 2, TT - 1) * DD + d0);
        const f32x4 vD = *(const f32x4*)(vb + (size_t)min(tr + 3, TT - 1) * DD + d0);

        // ---- k tile (no prefetch), convert immediately ----
        const int t = min(mt * 16 + lr, TT - 1);   // clamped; pad rows killed by bias
        const float* krow = kb + (size_t)t * DD;
        const f32x4 kc0 = *(const f32x4*)(krow + lg * 8);
        const f32x4 kc1 = *(const f32x4*)(krow + lg * 8 + 4);
        const f32x4 kc2 = *(const f32x4*)(krow + 32 + lg * 8);
        const f32x4 kc3 = *(const f32x4*)(krow + 32 + lg * 8 + 4);

        half8 af0, af1;
#pragma unroll
        for (int j = 0; j < 4; ++j) {
            af0[j] = (_Float16)kc0[j];  af0[j + 4] = (_Float16)kc1[j];
            af1[j] = (_Float16)kc2[j];  af1[j + 4] = (_Float16)kc3[j];
        }
        // q fragments from LDS (broadcast within lg group, conflict-free)
        const half8 qh0 = *(const half8*)(myQ + lg * 8);
        const half8 qh1 = *(const half8*)(myQ + 32 + lg * 8);
        const half8 af2 = qh0 * af0;
        const half8 af3 = qh1 * af1;

        // ---- layer 1 MFMA, qh folded into C-init, relu -> per-wave LDS ----
#pragma unroll
        for (int n = 0; n < 5; ++n) {
            f32x4 a = { qhr[n], qhr[n], qhr[n], qhr[n] };
            a = __builtin_amdgcn_mfma_f32_16x16x32_f16(af0, sF1v[(n * 4 + 0) * 64 + lane], a, 0, 0, 0);
            a = __builtin_amdgcn_mfma_f32_16x16x32_f16(af1, sF1v[(n * 4 + 1) * 64 + lane], a, 0, 0, 0);
            a = __builtin_amdgcn_mfma_f32_16x16x32_f16(af2, sF1v[(n * 4 + 2) * 64 + lane], a, 0, 0, 0);
            a = __builtin_amdgcn_mfma_f32_16x16x32_f16(af3, sF1v[(n * 4 + 3) * 64 + lane], a, 0, 0, 0);
            const int slot   = (n * 16 + lr) >> 3;
            const int within = ((n * 16 + lr) & 7) * 2;
#pragma unroll
            for (int j = 0; j < 4; ++j) {
                const int r = lg * 4 + j;
                *(_Float16*)(myH1 + r * 192 + ((slot ^ (r & 3)) << 4) + within) = (_Float16)fmaxf(a[j], 0.f);
            }
        }

        // ---- layer 2 (wave-private rows), b2 folded into C-init ----
        const half8 a2_0 = *(const half8*)(myH1 + lr * 192 + (((0 + lg) ^ (lr & 3)) << 4));
        const half8 a2_1 = *(const half8*)(myH1 + lr * 192 + (((4 + lg) ^ (lr & 3)) << 4));
        const half8 a2_2 = *(const half8*)(myH1 + lr * 192 + (((8 + lg) ^ (lr & 3)) << 4));

        float p0 = 0.f, p1 = 0.f, p2 = 0.f, p3 = 0.f;
#pragma unroll
        for (int n = 0; n < 3; ++n) {
            f32x4 c2 = { bbr[n], bbr[n], bbr[n], bbr[n] };
            c2 = __builtin_amdgcn_mfma_f32_16x16x32_f16(a2_0, sF2v[(n * 3 + 0) * 64 + lane], c2, 0, 0, 0);
            c2 = __builtin_amdgcn_mfma_f32_16x16x32_f16(a2_1, sF2v[(n * 3 + 1) * 64 + lane], c2, 0, 0, 0);
            c2 = __builtin_amdgcn_mfma_f32_16x16x32_f16(a2_2, sF2v[(n * 3 + 2) * 64 + lane], c2, 0, 0, 0);
            p0 = fmaf(fmaxf(c2[0], 0.f), wfr[n], p0);
            p1 = fmaf(fmaxf(c2[1], 0.f), wfr[n], p1);
            p2 = fmaf(fmaxf(c2[2], 0.f), wfr[n], p2);
            p3 = fmaf(fmaxf(c2[3], 0.f), wfr[n], p3);
        }
        // butterfly over the 16-lane column group: rows lg*4+{0..3} summed
#pragma unroll
        for (int off = 1; off < 16; off <<= 1) {
            p0 += __shfl_xor(p0, off);
            p1 += __shfl_xor(p1, off);
            p2 += __shfl_xor(p2, off);
            p3 += __shfl_xor(p3, off);
        }

        // ---- group-private online masked softmax + v accumulation ----
        const f32x4 bias4 = *(const f32x4*)&sBias[wid][mt * 16 + lg * 4];
        const float l0 = fminf(p0, bias4[0]) + bfv;
        const float l1 = fminf(p1, bias4[1]) + bfv;
        const float l2 = fminf(p2, bias4[2]) + bfv;
        const float l3 = fminf(p3, bias4[3]) + bfv;
        const float lmax = fmaxf(fmaxf(l0, l1), fmaxf(l2, l3));
        const float mnew = fmaxf(m, lmax);
        const float sc = __expf(m - mnew);
        const float w0 = __expf(l0 - mnew);
        const float w1 = __expf(l1 - mnew);
        const float w2 = __expf(l2 - mnew);
        const float w3 = __expf(l3 - mnew);
        s = s * sc + (w0 + w1 + w2 + w3);
        acc *= sc;
        acc += vA * w0;
        acc += vB * w1;
        acc += vC * w2;
        acc += vD * w3;
        m = mnew;
    }

    // ---- merge the 4 group states (lanes differ in bits 4,5) ----
    float mo = fmaxf(m, __shfl_xor(m, 16));
    mo = fmaxf(mo, __shfl_xor(mo, 32));
    const float f = __expf(m - mo);
    s *= f;
    acc *= f;
    s += __shfl_xor(s, 16);
    s += __shfl_xor(s, 32);
#pragma unroll
    for (int e = 0; e < 4; ++e) {
        float t = acc[e];
        t += __shfl_xor(t, 16);
        t += __shfl_xor(t, 32);
        acc[e] = t;
    }
    if (lg == 0) {
        const f32x4 res = acc / s;
        *(f32x4*)(out + (size_t)b * DD + d0) = res;
    }
}

extern "C" void kernel_launch(void* const* d_in, const int* in_sizes, int n_in,
                              void* d_out, int out_size, void* d_ws, size_t ws_size,
                              hipStream_t stream)
{
    const float* q   = (const float*)d_in[0];
    const float* k   = (const float*)d_in[1];
    const float* v   = (const float*)d_in[2];
    const int*  mask = (const int*)  d_in[3];
    const float* W1  = (const float*)d_in[4];
    const float* b1  = (const float*)d_in[5];
    const float* W2  = (const float*)d_in[6];
    const float* b2  = (const float*)d_in[7];
    const float* Wf  = (const float*)d_in[8];
    const float* bf  = (const float*)d_in[9];
    float* out = (float*)d_out;

    char* ws = (char*)d_ws;
    float*    wQh = (float*)   (ws + OFF_QH);
    _Float16* wF1 = (_Float16*)(ws + OFF_F1);
    _Float16* wF2 = (_Float16*)(ws + OFF_F2);

    prep_weights<<<16, 256, 0, stream>>>(W1, W2, wF1, wF2);
    prep_qh<<<(NB * NH1 + 255) / 256, 256, 0, stream>>>(q, W1, b1, wQh);
    attn_main<<<NB / 4, 256, 0, stream>>>(q, k, v, mask, Wf, b2, bf, wQh, wF1, wF2, out);
}

// Round 13
// 103.060 us; speedup vs baseline: 2.6911x; 2.6911x over previous
//
#include <hip/hip_runtime.h>
#include <cstddef>
#include <cmath>

#define NB  4096
#define TT  200
#define DD  64
#define NH1 80
#define NH2 40

typedef _Float16 half8 __attribute__((ext_vector_type(8)));
typedef float    f32x4 __attribute__((ext_vector_type(4)));

// ---- workspace layout (bytes) ----
static const size_t OFF_QH = 0;
static const size_t OFF_F1 = (size_t)NB * NH1 * 4;
static const size_t OFF_F2 = OFF_F1 + (size_t)5 * 4 * 64 * 8 * 2;

__global__ void prep_weights(const float* __restrict__ W1, const float* __restrict__ W2,
                             _Float16* __restrict__ wF1, _Float16* __restrict__ wF2)
{
    const int tid = blockIdx.x * blockDim.x + threadIdx.x;
    const int stride = blockDim.x * gridDim.x;
    for (int i = tid; i < 5 * 4 * 64 * 8; i += stride) {
        const int j = i & 7, l = (i >> 3) & 63, s = (i >> 9) & 3, n = i >> 11;
        const int h  = n * 16 + (l & 15);
        const int kk = s * 32 + (l >> 4) * 8 + j;
        const float w = (kk < 64) ? (W1[(64 + kk) * NH1 + h] - W1[(128 + kk) * NH1 + h])
                                  :  W1[(128 + kk) * NH1 + h];
        wF1[i] = (_Float16)w;
    }
    for (int i = tid; i < 3 * 3 * 64 * 8; i += stride) {
        const int j = i & 7, l = (i >> 3) & 63;
        const int s = (i >> 9) % 3, n = i / 1536;
        const int kk = s * 32 + (l >> 4) * 8 + j;
        const int n2 = n * 16 + (l & 15);
        const float w = (kk < NH1 && n2 < NH2) ? W2[kk * NH2 + n2] : 0.f;
        wF2[i] = (_Float16)w;
    }
}

__global__ void prep_qh(const float* __restrict__ q, const float* __restrict__ W1,
                        const float* __restrict__ b1, float* __restrict__ wQh)
{
    const int idx = blockIdx.x * blockDim.x + threadIdx.x;
    if (idx >= NB * NH1) return;
    const int b = idx / NH1;
    const int h = idx - b * NH1;
    const float* qb = q + (size_t)b * DD;
    float acc = b1[h];
#pragma unroll 8
    for (int d = 0; d < DD; ++d)
        acc += qb[d] * (W1[d * NH1 + h] + W1[(128 + d) * NH1 + h]);
    wQh[idx] = acc;
}

// one wave per b; group-split online softmax; weights + q(fp16) in LDS;
// v register ping-pong double-buffer (loads in flight ~2 tile periods)
__global__ __launch_bounds__(256, 2)
void attn_main(const float* __restrict__ q, const float* __restrict__ k,
               const float* __restrict__ v, const int* __restrict__ mask,
               const float* __restrict__ Wf, const float* __restrict__ b2g,
               const float* __restrict__ bf,
               const float* __restrict__ wQh, const _Float16* __restrict__ wF1,
               const _Float16* __restrict__ wF2, float* __restrict__ out)
{
    __shared__ __align__(16) _Float16 sWF1[5 * 4 * 64 * 8];   // 20480 B
    __shared__ __align__(16) _Float16 sWF2[3 * 3 * 64 * 8];   //  9216 B
    __shared__ __align__(16) char sH1[4 * 3072];              // per-wave h1 (12288 B)
    __shared__ __align__(16) float sBias[4][208];             //  3328 B
    __shared__ __align__(16) _Float16 sQ16[4 * 64];           //   512 B

    const int tid  = threadIdx.x;
    const int wid  = tid >> 6;
    const int lane = tid & 63;
    const int lr   = lane & 15;
    const int lg   = lane >> 4;
    const int b    = blockIdx.x * 4 + wid;      // each wave owns one batch row
    const int d0   = lr * 4;                    // this lane's v/out column slice
    const float bfv = bf[0];

    // stage weight fragments into LDS (block-shared)
    {
        f32x4* dst1 = (f32x4*)sWF1;
        const f32x4* src1 = (const f32x4*)wF1;
        for (int i = tid; i < 1280; i += 256) dst1[i] = src1[i];
        f32x4* dst2 = (f32x4*)sWF2;
        const f32x4* src2 = (const f32x4*)wF2;
        for (int i = tid; i < 576; i += 256) dst2[i] = src2[i];
    }

    // per-wave q in fp16 LDS (one element per lane)
    sQ16[wid * 64 + lane] = (_Float16)q[(size_t)b * DD + lane];

    // per-wave mask bias: +big = keep, CONST_MIN = masked, -inf = pad rows (t>=200)
    for (int i = lane; i < 208; i += 64) {
        float bv;
        if (i < TT) bv = mask[(size_t)b * TT + i] ? 3.0e38f : -4294967295.0f;
        else        bv = -INFINITY;
        sBias[wid][i] = bv;
    }

    // per-lane slices of qh / Wf / b2
    float qhr[5];
#pragma unroll
    for (int n = 0; n < 5; ++n) qhr[n] = wQh[(size_t)b * NH1 + n * 16 + lr];
    float wfr[3], bbr[3];
#pragma unroll
    for (int n = 0; n < 3; ++n) {
        const int hc = n * 16 + lr;
        wfr[n] = (hc < NH2) ? Wf[hc]  : 0.f;
        bbr[n] = (hc < NH2) ? b2g[hc] : 0.f;
    }

    // zero-pad my wave's h1 cols 80..95 (slots 10,11), swizzled
    char* myH1 = sH1 + wid * 3072;
    if (lane < 32) {
        const int row = lane >> 1;
        const int slotL = 10 + (lane & 1);
        const f32x4 z4 = {};
        *(f32x4*)(myH1 + row * 192 + ((slotL ^ (row & 3)) << 4)) = z4;
    }

    __syncthreads();   // sWF1 / sWF2 / sQ16 ready

    const half8* sF1v = (const half8*)sWF1;
    const half8* sF2v = (const half8*)sWF2;
    const float* vb   = v + (size_t)b * (TT * DD);
    const float* kb   = k + (size_t)b * (TT * DD);
    const _Float16* myQ = sQ16 + wid * 64;

    // per-GROUP online softmax state
    float m = -INFINITY, s = 0.f;
    f32x4 acc = {};

    // v ping-pong: prologue issues tile 0 loads
    f32x4 vA0, vA1, vA2, vA3;
    {
        const int tr = lg * 4;   // rows 0..15, no clamp needed
        vA0 = *(const f32x4*)(vb + (size_t)(tr + 0) * DD + d0);
        vA1 = *(const f32x4*)(vb + (size_t)(tr + 1) * DD + d0);
        vA2 = *(const f32x4*)(vb + (size_t)(tr + 2) * DD + d0);
        vA3 = *(const f32x4*)(vb + (size_t)(tr + 3) * DD + d0);
    }

    for (int mt = 0; mt < 13; ++mt) {
        // ---- issue NEXT tile's v loads (buffer B) — in flight across this whole tile ----
        f32x4 vB0, vB1, vB2, vB3;
        if (mt < 12) {
            const int tr = (mt + 1) * 16 + lg * 4;
            vB0 = *(const f32x4*)(vb + (size_t)min(tr + 0, TT - 1) * DD + d0);
            vB1 = *(const f32x4*)(vb + (size_t)min(tr + 1, TT - 1) * DD + d0);
            vB2 = *(const f32x4*)(vb + (size_t)min(tr + 2, TT - 1) * DD + d0);
            vB3 = *(const f32x4*)(vb + (size_t)min(tr + 3, TT - 1) * DD + d0);
        }

        // ---- k tile, convert immediately ----
        const int t = min(mt * 16 + lr, TT - 1);
        const float* krow = kb + (size_t)t * DD;
        const f32x4 kc0 = *(const f32x4*)(krow + lg * 8);
        const f32x4 kc1 = *(const f32x4*)(krow + lg * 8 + 4);
        const f32x4 kc2 = *(const f32x4*)(krow + 32 + lg * 8);
        const f32x4 kc3 = *(const f32x4*)(krow + 32 + lg * 8 + 4);

        half8 af0, af1;
#pragma unroll
        for (int j = 0; j < 4; ++j) {
            af0[j] = (_Float16)kc0[j];  af0[j + 4] = (_Float16)kc1[j];
            af1[j] = (_Float16)kc2[j];  af1[j + 4] = (_Float16)kc3[j];
        }
        const half8 qf0 = *(const half8*)(myQ + lg * 8);
        const half8 qf1 = *(const half8*)(myQ + 32 + lg * 8);
        const half8 af2 = qf0 * af0;
        const half8 af3 = qf1 * af1;

        // ---- layer 1 MFMA, qh folded into C-init, relu -> per-wave LDS ----
#pragma unroll
        for (int n = 0; n < 5; ++n) {
            f32x4 a = { qhr[n], qhr[n], qhr[n], qhr[n] };
            a = __builtin_amdgcn_mfma_f32_16x16x32_f16(af0, sF1v[(n * 4 + 0) * 64 + lane], a, 0, 0, 0);
            a = __builtin_amdgcn_mfma_f32_16x16x32_f16(af1, sF1v[(n * 4 + 1) * 64 + lane], a, 0, 0, 0);
            a = __builtin_amdgcn_mfma_f32_16x16x32_f16(af2, sF1v[(n * 4 + 2) * 64 + lane], a, 0, 0, 0);
            a = __builtin_amdgcn_mfma_f32_16x16x32_f16(af3, sF1v[(n * 4 + 3) * 64 + lane], a, 0, 0, 0);
            const int slot   = (n * 16 + lr) >> 3;
            const int within = ((n * 16 + lr) & 7) * 2;
#pragma unroll
            for (int j = 0; j < 4; ++j) {
                const int r = lg * 4 + j;
                *(_Float16*)(myH1 + r * 192 + ((slot ^ (r & 3)) << 4) + within) = (_Float16)fmaxf(a[j], 0.f);
            }
        }

        // ---- layer 2 (wave-private rows), b2 folded into C-init ----
        const half8 a2_0 = *(const half8*)(myH1 + lr * 192 + (((0 + lg) ^ (lr & 3)) << 4));
        const half8 a2_1 = *(const half8*)(myH1 + lr * 192 + (((4 + lg) ^ (lr & 3)) << 4));
        const half8 a2_2 = *(const half8*)(myH1 + lr * 192 + (((8 + lg) ^ (lr & 3)) << 4));

        float p0 = 0.f, p1 = 0.f, p2 = 0.f, p3 = 0.f;
#pragma unroll
        for (int n = 0; n < 3; ++n) {
            f32x4 c2 = { bbr[n], bbr[n], bbr[n], bbr[n] };
            c2 = __builtin_amdgcn_mfma_f32_16x16x32_f16(a2_0, sF2v[(n * 3 + 0) * 64 + lane], c2, 0, 0, 0);
            c2 = __builtin_amdgcn_mfma_f32_16x16x32_f16(a2_1, sF2v[(n * 3 + 1) * 64 + lane], c2, 0, 0, 0);
            c2 = __builtin_amdgcn_mfma_f32_16x16x32_f16(a2_2, sF2v[(n * 3 + 2) * 64 + lane], c2, 0, 0, 0);
            p0 = fmaf(fmaxf(c2[0], 0.f), wfr[n], p0);
            p1 = fmaf(fmaxf(c2[1], 0.f), wfr[n], p1);
            p2 = fmaf(fmaxf(c2[2], 0.f), wfr[n], p2);
            p3 = fmaf(fmaxf(c2[3], 0.f), wfr[n], p3);
        }
#pragma unroll
        for (int off = 1; off < 16; off <<= 1) {
            p0 += __shfl_xor(p0, off);
            p1 += __shfl_xor(p1, off);
            p2 += __shfl_xor(p2, off);
            p3 += __shfl_xor(p3, off);
        }

        // ---- group-private online masked softmax + v accumulation (buffer A) ----
        const f32x4 bias4 = *(const f32x4*)&sBias[wid][mt * 16 + lg * 4];
        const float l0 = fminf(p0, bias4[0]) + bfv;
        const float l1 = fminf(p1, bias4[1]) + bfv;
        const float l2 = fminf(p2, bias4[2]) + bfv;
        const float l3 = fminf(p3, bias4[3]) + bfv;
        const float lmax = fmaxf(fmaxf(l0, l1), fmaxf(l2, l3));
        const float mnew = fmaxf(m, lmax);
        const float sc = __expf(m - mnew);
        const float w0 = __expf(l0 - mnew);
        const float w1 = __expf(l1 - mnew);
        const float w2 = __expf(l2 - mnew);
        const float w3 = __expf(l3 - mnew);
        s = s * sc + (w0 + w1 + w2 + w3);
        acc *= sc;
        acc += vA0 * w0;
        acc += vA1 * w1;
        acc += vA2 * w2;
        acc += vA3 * w3;
        m = mnew;

        // ---- ping-pong swap ----
        if (mt < 12) {
            vA0 = vB0; vA1 = vB1; vA2 = vB2; vA3 = vB3;
        }
    }

    // ---- merge the 4 group states (lanes differ in bits 4,5) ----
    float mo = fmaxf(m, __shfl_xor(m, 16));
    mo = fmaxf(mo, __shfl_xor(mo, 32));
    const float f = __expf(m - mo);
    s *= f;
    acc *= f;
    s += __shfl_xor(s, 16);
    s += __shfl_xor(s, 32);
#pragma unroll
    for (int e = 0; e < 4; ++e) {
        float t = acc[e];
        t += __shfl_xor(t, 16);
        t += __shfl_xor(t, 32);
        acc[e] = t;
    }
    if (lg == 0) {
        const f32x4 res = acc / s;
        *(f32x4*)(out + (size_t)b * DD + d0) = res;
    }
}

extern "C" void kernel_launch(void* const* d_in, const int* in_sizes, int n_in,
                              void* d_out, int out_size, void* d_ws, size_t ws_size,
                              hipStream_t stream)
{
    const float* q   = (const float*)d_in[0];
    const float* k   = (const float*)d_in[1];
    const float* v   = (const float*)d_in[2];
    const int*  mask = (const int*)  d_in[3];
    const float* W1  = (const float*)d_in[4];
    const float* b1  = (const float*)d_in[5];
    const float* W2  = (const float*)d_in[6];
    const float* b2  = (const float*)d_in[7];
    const float* Wf  = (const float*)d_in[8];
    const float* bf  = (const float*)d_in[9];
    float* out = (float*)d_out;

    char* ws = (char*)d_ws;
    float*    wQh = (float*)   (ws + OFF_QH);
    _Float16* wF1 = (_Float16*)(ws + OFF_F1);
    _Float16* wF2 = (_Float16*)(ws + OFF_F2);

    prep_weights<<<16, 256, 0, stream>>>(W1, W2, wF1, wF2);
    prep_qh<<<(NB * NH1 + 255) / 256, 256, 0, stream>>>(q, W1, b1, wQh);
    attn_main<<<NB / 4, 256, 0, stream>>>(q, k, v, mask, Wf, b2, bf, wQh, wF1, wF2, out);
}